// Round 9
// baseline (399.288 us; speedup 1.0000x reference)
//
#include <hip/hip_runtime.h>
#include <stdint.h>

#define L_SEQ 2048
#define NB 2
#define EMB 2048
#define II 2048
#define NH 16
#define DH 128
#define MROWS (L_SEQ * NB)  // 4096

typedef __attribute__((ext_vector_type(8))) short bf16x8;
typedef __attribute__((ext_vector_type(4))) float f32x4;
typedef unsigned short u16;
typedef unsigned int u32;

__device__ __forceinline__ u16 f2bf(float f) {
  u32 u = __builtin_bit_cast(u32, f);
  u = u + 0x7fffu + ((u >> 16) & 1u);
  return (u16)(u >> 16);
}
__device__ __forceinline__ u16 f2bf_trunc(float f) {
  return (u16)(__builtin_bit_cast(u32, f) >> 16);
}

// async global->LDS, 16B/lane; HW dest = wave-uniform base + lane*16.
__device__ __forceinline__ void gl_lds16(const void* g, const u16* l) {
  __builtin_amdgcn_global_load_lds(
      (const __attribute__((address_space(1))) void*)(uintptr_t)g,
      (__attribute__((address_space(3))) void*)(u32)(uintptr_t)l, 16, 0, 0);
}

// All five f32->bf16 casts in one launch.
__global__ __launch_bounds__(256) void cast_all(
    const float* __restrict__ q, const float* __restrict__ w0, const float* __restrict__ w1,
    const float* __restrict__ w2, const float* __restrict__ w3, u16* __restrict__ dq,
    u16* __restrict__ dw) {
  const int b = blockIdx.x, t = threadIdx.x;
  const float* src;
  u16* dst;
  int idx;
  if (b < 8192) {
    src = q; dst = dq; idx = b * 256 + t;
  } else {
    int u = b - 8192;
    int sel = u >> 12;
    src = (sel == 0) ? w0 : (sel == 1) ? w1 : (sel == 2) ? w2 : w3;
    dst = dw + (size_t)sel * II * EMB;
    idx = (u & 4095) * 256 + t;
  }
  float4 v = ((const float4*)src)[idx];
  ushort4 o;
  o.x = f2bf(v.x); o.y = f2bf(v.y); o.z = f2bf(v.z); o.w = f2bf(v.w);
  ((ushort4*)dst)[idx] = o;
}

// V [head][L][DH] -> Vt [head][DH][L], 64-l x 128-d tiles.
__global__ __launch_bounds__(256) void transpose_v(const u16* __restrict__ V,
                                                   u16* __restrict__ Vt) {
  __shared__ u16 tile[128][72];
  const int lb = blockIdx.x * 64;
  const int h = blockIdx.y;
  const u16* src = V + (size_t)h * L_SEQ * DH;
  u16* dst = Vt + (size_t)h * DH * L_SEQ;
  const int t = threadIdx.x;
  {
    const int l = t & 63, d0 = (t >> 6) * 32;
#pragma unroll
    for (int c = 0; c < 4; c++) {
      uint4 u = *(const uint4*)(src + (size_t)(lb + l) * DH + d0 + c * 8);
      const u16* e = (const u16*)&u;
#pragma unroll
      for (int x = 0; x < 8; x++) tile[d0 + c * 8 + x][l] = e[x];
    }
  }
  __syncthreads();
  {
    const int d = t >> 1, lc = (t & 1) * 32;
#pragma unroll
    for (int c = 0; c < 4; c++) {
      uint4 u = *(const uint4*)&tile[d][lc + c * 8];
      *(uint4*)(dst + (size_t)d * L_SEQ + lb + lc + c * 8) = u;
    }
  }
}

// ---------------------------------------------------------------------------
// Unified GEMM v2.1: 128x256 tile, BK=64, 8 waves (2M x 4N, 64x64 per wave),
// register-pipelined K-loop (A 2-buf, B 3-buf LDS), RACE-FIXED vs v2:
// vmcnt is PER-WAVE, so frag reads of data staged by OTHER waves need a
// barrier AFTER the vmcnt. Body per K-tile (2 barriers, vs 4 in the 2-phase):
//   barrier(1)            // all waves' frag(T) reads done (lgkmcnt(0) below)
//   stage(T+2): 4xB -> b_sm[(T+2)%3], 2xA -> a_sm[T&1]   (A(T) region free)
//   vmcnt(6)              // own stage(T+1) portion complete
//   barrier(2)            // ALL waves' stage(T+1) visible
//   ds_read frags(T+1)    // issue first ...
//   32 MFMA on frags(T)   // ... MFMA overlaps LDS pipe (per-wave ILP)
//   lgkmcnt(0)            // pin reads in-body
// Window (2)->(1): reads touch a_sm[(T+1)&1]/b_sm[(T+1)%3]; in-flight
// stage(T+2) writes land in a_sm[T&1]/b_sm[(T+2)%3] — disjoint. Tails:
// T=NT-2 -> vmcnt(0); T=NT-1 -> no stage/read.
// ---------------------------------------------------------------------------
#define BK2 64
#define NT2 (EMB / BK2)  // 32

__global__ __launch_bounds__(512, 2) void gemm_2p(
    const u16* __restrict__ A, const u16* __restrict__ B, const float* __restrict__ b0,
    const float* __restrict__ b1, const float* __restrict__ b2, u16* __restrict__ out_bf,
    float* __restrict__ out_f, float qscale, int mode) {
  __shared__ __align__(16) u16 a_sm[2][8192];   // [buf][128 rows][64], chunk-swizzled
  __shared__ __align__(16) u16 b_sm[3][16384];  // [buf][256 rows][64], chunk-swizzled
  const int t = threadIdx.x;
  const int lane = t & 63, wv = t >> 6;
  const int quad = lane >> 4, l15 = lane & 15, x7 = l15 & 7;
  const int wm2 = wv >> 2, wn4 = wv & 3;        // wave tile 64x64 at (wm2*64, wn4*64)
  const int srow = lane >> 3;                   // row-in-8 within a 1KB stage unit
  const int schunk = (lane & 7) ^ (lane >> 3);  // inverse-swizzled global 16B chunk

  const int bid = blockIdx.x;
  const int cpx = gridDim.x >> 3;  // grid % 8 == 0 (768 or 256)
  const int swz = (bid & 7) * cpx + (bid >> 3);
  const int byy = swz & 31;        // 32 M-tiles (M=4096, BM=128)
  const int bxx = swz >> 5;        // N-tiles
  const int m0 = byy * 128, n0 = bxx * 256;

  const u16* abase = A + (size_t)m0 * EMB;
  const u16* bbase = B + (size_t)n0 * EMB;

  auto stageA = [&](int buf, int k0, int u) {  // u in 0..1 (64 rows each)
    int row = u * 64 + wv * 8 + srow;
    const u16* dst = (buf ? a_sm[1] : a_sm[0]) + u * 4096 + wv * 512;
    gl_lds16(abase + (size_t)row * EMB + k0 + schunk * 8, dst);
  };
  auto stageB = [&](int buf, int k0, int u) {  // u in 0..3, buf in 0..2
    int row = u * 64 + wv * 8 + srow;
    const u16* dst = (buf == 0 ? b_sm[0] : buf == 1 ? b_sm[1] : b_sm[2]) + u * 4096 + wv * 512;
    gl_lds16(bbase + (size_t)row * EMB + k0 + schunk * 8, dst);
  };

  // Prologue: tiles 0 and 1 fully staged + drained; frags(0) -> set0.
  stageB(0, 0, 0); stageB(0, 0, 1); stageB(0, 0, 2); stageB(0, 0, 3);
  stageA(0, 0, 0); stageA(0, 0, 1);
  stageB(1, BK2, 0); stageB(1, BK2, 1); stageB(1, BK2, 2); stageB(1, BK2, 3);
  stageA(1, BK2, 0); stageA(1, BK2, 1);
  __asm__ volatile("s_waitcnt vmcnt(0)" ::: "memory");
  __builtin_amdgcn_s_barrier();

  f32x4 acc[4][4] = {};
  bf16x8 afr0[4][2], bfr0[4][2], afr1[4][2], bfr1[4][2];

#pragma unroll
  for (int mi = 0; mi < 4; mi++)
#pragma unroll
    for (int ks = 0; ks < 2; ks++)
      afr0[mi][ks] = *(const bf16x8*)(a_sm[0] + wm2 * 4096 + (mi * 16 + l15) * 64 +
                                      ((ks * 4 + quad) ^ x7) * 8);
#pragma unroll
  for (int nj = 0; nj < 4; nj++)
#pragma unroll
    for (int ks = 0; ks < 2; ks++)
      bfr0[nj][ks] = *(const bf16x8*)(b_sm[0] + wn4 * 4096 + (nj * 16 + l15) * 64 +
                                      ((ks * 4 + quad) ^ x7) * 8);
  __asm__ volatile("s_waitcnt lgkmcnt(0)" ::: "memory");

#define GBODY(TT, AFRU, BFRU, AFRL, BFRL)                                               \
  {                                                                                     \
    __builtin_amdgcn_s_barrier(); /* (1) all waves' frag(TT) reads done */              \
    const int t2_ = (TT) + 2;                                                           \
    if (t2_ < NT2) {                                                                    \
      const int kk2_ = t2_ * BK2;                                                       \
      const int bb2_ = t2_ % 3;                                                         \
      stageB(bb2_, kk2_, 0); stageB(bb2_, kk2_, 1);                                     \
      stageB(bb2_, kk2_, 2); stageB(bb2_, kk2_, 3);                                     \
      stageA((TT) & 1, kk2_, 0); stageA((TT) & 1, kk2_, 1);                             \
      __asm__ volatile("s_waitcnt vmcnt(6)" ::: "memory");                              \
    } else if ((TT) + 1 < NT2) {                                                        \
      __asm__ volatile("s_waitcnt vmcnt(0)" ::: "memory");                              \
    }                                                                                   \
    __builtin_amdgcn_s_barrier(); /* (2) stage(TT+1) visible to ALL waves */            \
    if ((TT) + 1 < NT2) {                                                               \
      const u16* aN_ = (((TT) + 1) & 1) ? a_sm[1] : a_sm[0];                            \
      const int bn1_ = ((TT) + 1) % 3;                                                  \
      const u16* bN_ = bn1_ == 0 ? b_sm[0] : bn1_ == 1 ? b_sm[1] : b_sm[2];             \
      _Pragma("unroll") for (int mi = 0; mi < 4; mi++)                                  \
        _Pragma("unroll") for (int ks = 0; ks < 2; ks++)                                \
          AFRL[mi][ks] = *(const bf16x8*)(aN_ + wm2 * 4096 + (mi * 16 + l15) * 64 +     \
                                          ((ks * 4 + quad) ^ x7) * 8);                  \
      _Pragma("unroll") for (int nj = 0; nj < 4; nj++)                                  \
        _Pragma("unroll") for (int ks = 0; ks < 2; ks++)                                \
          BFRL[nj][ks] = *(const bf16x8*)(bN_ + wn4 * 4096 + (nj * 16 + l15) * 64 +     \
                                          ((ks * 4 + quad) ^ x7) * 8);                  \
    }                                                                                   \
    __builtin_amdgcn_s_setprio(1);                                                      \
    _Pragma("unroll") for (int ks = 0; ks < 2; ks++)                                    \
      _Pragma("unroll") for (int mi = 0; mi < 4; mi++)                                  \
        _Pragma("unroll") for (int nj = 0; nj < 4; nj++)                                \
          acc[mi][nj] = __builtin_amdgcn_mfma_f32_16x16x32_bf16(AFRU[mi][ks],           \
                            BFRU[nj][ks], acc[mi][nj], 0, 0, 0);                        \
    __builtin_amdgcn_s_setprio(0);                                                      \
    __asm__ volatile("s_waitcnt lgkmcnt(0)" ::: "memory");                              \
  }

#pragma unroll 1
  for (int tt = 0; tt < NT2; tt += 2) {
    GBODY(tt, afr0, bfr0, afr1, bfr1);
    GBODY(tt + 1, afr1, bfr1, afr0, bfr0);
  }
#undef GBODY

  // Epilogue.
  if (mode == 0) {
    const int mat = n0 >> 11;  // BN=256 divides 2048: block-uniform
    const float* bp = (mat == 0) ? b0 : (mat == 1) ? b1 : b2;
    const float sc2 = (mat == 0) ? qscale : 1.0f;
#pragma unroll
    for (int mi = 0; mi < 4; mi++) {
#pragma unroll
      for (int nj = 0; nj < 4; nj++) {
#pragma unroll
        for (int r = 0; r < 4; r++) {
          int row = m0 + wm2 * 64 + mi * 16 + quad * 4 + r;
          int col = n0 + wn4 * 64 + nj * 16 + l15;
          int cc = col & 2047;
          float v = (acc[mi][nj][r] + bp[cc]) * sc2;
          int l = row >> 1, nb = row & 1;
          int hh = cc >> 7, dd = cc & 127;
          out_bf[(size_t)mat * MROWS * II + ((size_t)(nb * NH + hh) * L_SEQ + l) * DH + dd] =
              f2bf(v);
        }
      }
    }
  } else {
#pragma unroll
    for (int mi = 0; mi < 4; mi++) {
#pragma unroll
      for (int nj = 0; nj < 4; nj++) {
#pragma unroll
        for (int r = 0; r < 4; r++) {
          int row = m0 + wm2 * 64 + mi * 16 + quad * 4 + r;
          int col = n0 + wn4 * 64 + nj * 16 + l15;
          out_f[(size_t)row * EMB + col] = acc[mi][nj][r] + b0[col];
        }
      }
    }
  }
}

// ---------------------------------------------------------------------------
// Causal flash attention v6 (kept from R6): KVBLK=64, double-buffered K/V,
// wave-private P, one block barrier per iteration; stage(jb+1) issued at top
// of iter jb overlaps the whole iteration.
// ---------------------------------------------------------------------------
__global__ __launch_bounds__(256, 2) void flash_attn(
    const u16* __restrict__ Qh, const u16* __restrict__ Kh, const u16* __restrict__ Vt,
    u16* __restrict__ ctx) {
  __shared__ __align__(16) u16 k_sm[2][64 * 128];  // [buf][key][d], chunk-swizzled
  __shared__ __align__(16) u16 v_sm[2][128 * 64];  // [buf][d][key], chunk-swizzled
  __shared__ __align__(16) u16 p_sm[4][32 * 64];   // [wave][qrow][key], chunk-swizzled
  const int bx = blockIdx.x;
  const int nh = ((bx & 7) << 2) | ((bx >> 3) & 3);  // 4 heads per XCD
  const int g = (bx >> 5) & 7;
  const int qt = (bx < 256) ? (15 - g) : g;
  const int q0 = qt * 128;
  const int nK = 2 * (qt + 1);
  const int t = threadIdx.x;
  const int lane = t & 63, wv = t >> 6;
  const int quad = lane >> 4, l15 = lane & 15;
  const int x7 = l15 & 7;
  const size_t hq = (size_t)nh * L_SEQ * DH;
  const u16* qp = Qh + hq;
  const u16* kp = Kh + hq;
  const u16* vp = Vt + hq;  // [DH][L]
  const int n = nh >> 4, h = nh & 15;
  const int srow = lane >> 4;  // K staging: row-in-4 (256B rows)
  const int spos = lane & 15;
  const int vrow = lane >> 3;  // V staging: row-in-8 (128B rows)
  const int vpos = lane & 7;
  u16* pwb = p_sm[wv];  // per-wave 4KB P slice

  auto stageKV = [&](int bb, int kb) {
#pragma unroll
    for (int i = 0; i < 4; i++) {
      int ci = wv * 4 + i;  // 16 1KB units each for K and V
      int krow = ci * 4 + srow;                    // 0..63
      int gck = spos ^ (krow & 7);
      gl_lds16(kp + (size_t)(kb + krow) * DH + gck * 8,
               (bb ? k_sm[1] : k_sm[0]) + ci * 512);
      int drow = ci * 8 + vrow;                    // 0..127
      int gcv = vpos ^ (drow & 7);
      gl_lds16(vp + (size_t)drow * L_SEQ + kb + gcv * 8,
               (bb ? v_sm[1] : v_sm[0]) + ci * 512);
    }
  };

  bf16x8 qf[2][4];
#pragma unroll
  for (int mi = 0; mi < 2; mi++)
#pragma unroll
    for (int ks = 0; ks < 4; ks++)
      qf[mi][ks] = *(const bf16x8*)(qp + (size_t)(q0 + wv * 32 + mi * 16 + l15) * DH +
                                    ks * 32 + quad * 8);

  f32x4 o_acc[2][8] = {};
  float l_part[2][4] = {};

  stageKV(0, 0);  // prologue: tile 0 -> buf 0

#pragma unroll 1
  for (int jb = 0; jb < nK; jb++) {
    const int b = jb & 1;
    const u16* kbuf = b ? k_sm[1] : k_sm[0];
    const u16* vbuf = b ? v_sm[1] : v_sm[0];
    const int kb = jb * 64;

    __syncthreads();
    if (jb + 1 < nK) stageKV(b ^ 1, kb + 64);  // overlaps this whole iteration

    // S = Q K^T
    f32x4 s[2][4] = {};
    __builtin_amdgcn_s_setprio(1);
#pragma unroll
    for (int nt = 0; nt < 4; nt++) {
#pragma unroll
      for (int ks = 0; ks < 4; ks++) {
        bf16x8 kf = *(const bf16x8*)(kbuf + (nt * 16 + l15) * 128 + ((ks * 4 + quad) ^ x7) * 8);
#pragma unroll
        for (int mi = 0; mi < 2; mi++)
          s[mi][nt] = __builtin_amdgcn_mfma_f32_16x16x32_bf16(qf[mi][ks], kf, s[mi][nt], 0, 0, 0);
      }
    }
    __builtin_amdgcn_s_setprio(0);

    // Softmax -> wave-private P (no block sync needed).
    const bool diag = (jb >= nK - 2);
#pragma unroll
    for (int mi = 0; mi < 2; mi++) {
      const int rowg = q0 + wv * 32 + mi * 16 + quad * 4;
#pragma unroll
      for (int nt = 0; nt < 4; nt++) {
        const int colg = kb + nt * 16 + l15;
#pragma unroll
        for (int r = 0; r < 4; r++) {
          float p = __builtin_amdgcn_exp2f(s[mi][nt][r]);
          if (diag && colg > rowg + r) p = 0.f;
          l_part[mi][r] += p;
          int pr = mi * 16 + quad * 4 + r;
          int chunk = nt * 2 + (l15 >> 3);
          int pos = chunk ^ (pr & 7);
          pwb[pr * 64 + pos * 8 + (l15 & 7)] = f2bf_trunc(p);
        }
      }
    }
    __asm__ volatile("s_waitcnt lgkmcnt(0)" ::: "memory");
    __builtin_amdgcn_sched_barrier(0);

    // O += P V
    bf16x8 pf[2][2];
#pragma unroll
    for (int mi = 0; mi < 2; mi++)
#pragma unroll
      for (int ks = 0; ks < 2; ks++)
        pf[mi][ks] = *(const bf16x8*)(pwb + (mi * 16 + l15) * 64 + ((ks * 4 + quad) ^ x7) * 8);
    __builtin_amdgcn_s_setprio(1);
#pragma unroll
    for (int nt = 0; nt < 8; nt++) {
#pragma unroll
      for (int ks = 0; ks < 2; ks++) {
        bf16x8 vf = *(const bf16x8*)(vbuf + (nt * 16 + l15) * 64 + ((ks * 4 + quad) ^ x7) * 8);
#pragma unroll
        for (int mi = 0; mi < 2; mi++)
          o_acc[mi][nt] =
              __builtin_amdgcn_mfma_f32_16x16x32_bf16(pf[mi][ks], vf, o_acc[mi][nt], 0, 0, 0);
      }
    }
    __builtin_amdgcn_s_setprio(0);
  }

  // Epilogue: reduce denominators across the 16-lane row group, write ctx.
#pragma unroll
  for (int mi = 0; mi < 2; mi++) {
#pragma unroll
    for (int r = 0; r < 4; r++) {
      float lv = l_part[mi][r];
#pragma unroll
      for (int off = 1; off < 16; off <<= 1) lv += __shfl_xor(lv, off, 64);
      float inv = 1.f / lv;
      const int lrow = q0 + wv * 32 + mi * 16 + quad * 4 + r;
#pragma unroll
      for (int nt = 0; nt < 8; nt++) {
        int dd = nt * 16 + l15;
        ctx[((size_t)lrow * NB + n) * EMB + h * DH + dd] = f2bf(o_acc[mi][nt][r] * inv);
      }
    }
  }
}

extern "C" void kernel_launch(void* const* d_in, const int* in_sizes, int n_in,
                              void* d_out, int out_size, void* d_ws, size_t ws_size,
                              hipStream_t stream) {
  const float* query    = (const float*)d_in[0];
  const float* q_proj   = (const float*)d_in[1];
  const float* q_bias   = (const float*)d_in[2];
  const float* k_proj   = (const float*)d_in[3];
  const float* k_bias   = (const float*)d_in[4];
  const float* v_proj   = (const float*)d_in[5];
  const float* v_bias   = (const float*)d_in[6];
  const float* out_proj = (const float*)d_in[7];
  const float* out_bias = (const float*)d_in[8];

  u16* ws  = (u16*)d_ws;
  u16* Xbf = ws;                                  // 4096x2048 (dead after QKV gemm)
  u16* Wq  = Xbf + (size_t)MROWS * EMB;           // Wq|Wk|Wv contiguous = [6144,2048]
  u16* Wk  = Wq + (size_t)II * EMB;
  u16* Wv  = Wk + (size_t)II * EMB;
  u16* Wo  = Wv + (size_t)II * EMB;
  u16* Qw  = Wo + (size_t)EMB * II;               // [NB*NH][L][DH], Q|K|V contiguous
  u16* Kw  = Qw + (size_t)MROWS * II;
  u16* Vw  = Kw + (size_t)MROWS * II;
  u16* Cw  = Vw + (size_t)MROWS * II;             // ctx [L][NB][EMB]
  u16* Vtb = Xbf;                                 // Vt [NB*NH][DH][L] aliases Xbf

  cast_all<<<8192 + 4 * 4096, 256, 0, stream>>>(query, q_proj, k_proj, v_proj, out_proj,
                                                Xbf, Wq);

  // d^-0.5 * log2(e): base-2 softmax
  const float qscale = 0.08838834764831845f * 1.4426950408889634f;
  gemm_2p<<<768, 512, 0, stream>>>(Xbf, Wq, q_bias, k_bias, v_bias, Qw, nullptr, qscale, 0);

  transpose_v<<<dim3(L_SEQ / 64, NB * NH), 256, 0, stream>>>(Vw, Vtb);

  flash_attn<<<512, 256, 0, stream>>>(Qw, Kw, Vtb, Cw);

  gemm_2p<<<256, 512, 0, stream>>>(Cw, Wo, out_bias, nullptr, nullptr, nullptr,
                                   (float*)d_out, 1.0f, 1);
}

// Round 10
// 367.624 us; speedup vs baseline: 1.0861x; 1.0861x over previous
//
#include <hip/hip_runtime.h>
#include <stdint.h>

#define L_SEQ 2048
#define NB 2
#define EMB 2048
#define II 2048
#define NH 16
#define DH 128
#define MROWS (L_SEQ * NB)  // 4096

typedef __attribute__((ext_vector_type(8))) short bf16x8;
typedef __attribute__((ext_vector_type(4))) float f32x4;
typedef unsigned short u16;
typedef unsigned int u32;

__device__ __forceinline__ u16 f2bf(float f) {
  u32 u = __builtin_bit_cast(u32, f);
  u = u + 0x7fffu + ((u >> 16) & 1u);
  return (u16)(u >> 16);
}
__device__ __forceinline__ u16 f2bf_trunc(float f) {
  return (u16)(__builtin_bit_cast(u32, f) >> 16);
}

// async global->LDS, 16B/lane; HW dest = wave-uniform base + lane*16.
__device__ __forceinline__ void gl_lds16(const void* g, const u16* l) {
  __builtin_amdgcn_global_load_lds(
      (const __attribute__((address_space(1))) void*)(uintptr_t)g,
      (__attribute__((address_space(3))) void*)(u32)(uintptr_t)l, 16, 0, 0);
}

// All five f32->bf16 casts in one launch.
__global__ __launch_bounds__(256) void cast_all(
    const float* __restrict__ q, const float* __restrict__ w0, const float* __restrict__ w1,
    const float* __restrict__ w2, const float* __restrict__ w3, u16* __restrict__ dq,
    u16* __restrict__ dw) {
  const int b = blockIdx.x, t = threadIdx.x;
  const float* src;
  u16* dst;
  int idx;
  if (b < 8192) {
    src = q; dst = dq; idx = b * 256 + t;
  } else {
    int u = b - 8192;
    int sel = u >> 12;
    src = (sel == 0) ? w0 : (sel == 1) ? w1 : (sel == 2) ? w2 : w3;
    dst = dw + (size_t)sel * II * EMB;
    idx = (u & 4095) * 256 + t;
  }
  float4 v = ((const float4*)src)[idx];
  ushort4 o;
  o.x = f2bf(v.x); o.y = f2bf(v.y); o.z = f2bf(v.z); o.w = f2bf(v.w);
  ((ushort4*)dst)[idx] = o;
}

// ---------------------------------------------------------------------------
// Unified GEMM (R5-proven): 128x256 tile, BK=64, 8 waves (2M x 4N, 64x64 per
// wave), 2 phases per K-tile, deep pipeline (A 2-buf, B 3-buf).
// QKV: grid 768 = 3.0 rounds, 121 us. out-proj: grid 256 = 1.0 round.
// (R9's register-pipelined variant regressed 121->145; reverted.)
// ---------------------------------------------------------------------------
#define BK2 64
#define NT2 (EMB / BK2)  // 32

__global__ __launch_bounds__(512, 2) void gemm_2p(
    const u16* __restrict__ A, const u16* __restrict__ B, const float* __restrict__ b0,
    const float* __restrict__ b1, const float* __restrict__ b2, u16* __restrict__ out_bf,
    float* __restrict__ out_f, float qscale, int mode) {
  __shared__ __align__(16) u16 a_sm[2][8192];   // [buf][128 rows][64], chunk-swizzled
  __shared__ __align__(16) u16 b_sm[3][16384];  // [buf][256 rows][64], chunk-swizzled
  const int t = threadIdx.x;
  const int lane = t & 63, wv = t >> 6;
  const int quad = lane >> 4, l15 = lane & 15, x7 = l15 & 7;
  const int wm2 = wv >> 2, wn4 = wv & 3;        // wave tile 64x64 at (wm2*64, wn4*64)
  const int srow = lane >> 3;                   // row-in-8 within a 1KB stage unit
  const int schunk = (lane & 7) ^ (lane >> 3);  // inverse-swizzled global 16B chunk

  const int bid = blockIdx.x;
  const int cpx = gridDim.x >> 3;  // grid % 8 == 0 (768 or 256)
  const int swz = (bid & 7) * cpx + (bid >> 3);
  const int byy = swz & 31;        // 32 M-tiles (M=4096, BM=128)
  const int bxx = swz >> 5;        // N-tiles
  const int m0 = byy * 128, n0 = bxx * 256;

  const u16* abase = A + (size_t)m0 * EMB;
  const u16* bbase = B + (size_t)n0 * EMB;

  auto stageA = [&](int buf, int k0, int u) {  // u in 0..1 (64 rows each)
    int row = u * 64 + wv * 8 + srow;
    const u16* dst = (buf ? a_sm[1] : a_sm[0]) + u * 4096 + wv * 512;
    gl_lds16(abase + (size_t)row * EMB + k0 + schunk * 8, dst);
  };
  auto stageB = [&](int buf, int k0, int u) {  // u in 0..3, buf in 0..2
    int row = u * 64 + wv * 8 + srow;
    const u16* dst = (buf == 0 ? b_sm[0] : buf == 1 ? b_sm[1] : b_sm[2]) + u * 4096 + wv * 512;
    gl_lds16(bbase + (size_t)row * EMB + k0 + schunk * 8, dst);
  };

  // Prologue: tiles 0 and 1 fully staged, drained.
  stageB(0, 0, 0); stageB(0, 0, 1); stageB(0, 0, 2); stageB(0, 0, 3);
  stageA(0, 0, 0); stageA(0, 0, 1);
  stageB(1, BK2, 0); stageB(1, BK2, 1); stageB(1, BK2, 2); stageB(1, BK2, 3);
  stageA(1, BK2, 0); stageA(1, BK2, 1);
  __asm__ volatile("s_waitcnt vmcnt(0)" ::: "memory");
  __builtin_amdgcn_s_barrier();

  f32x4 acc[4][4] = {};
  int tB = 0;  // B buffer holding tile tt

#pragma unroll 1
  for (int tt = 0; tt < NT2; ++tt) {
    const u16* aC = (tt & 1) ? a_sm[1] : a_sm[0];
    const u16* bC = (tB == 0) ? b_sm[0] : (tB == 1) ? b_sm[1] : b_sm[2];
    const int tB2 = (tB + 2 >= 3) ? tB - 1 : tB + 2;  // (tB+2)%3
    const int kk2 = (tt + 2) * BK2;
    const bool pf2 = (tt + 2 < NT2);

    bf16x8 afr[4][2];  // A frags live across both phases

    // ---- phase 0: nj 0..1; stage B(T+2) x4 ----
    {
#pragma unroll
      for (int mi = 0; mi < 4; mi++)
#pragma unroll
        for (int ks = 0; ks < 2; ks++)
          afr[mi][ks] = *(const bf16x8*)(aC + wm2 * 4096 + (mi * 16 + l15) * 64 +
                                         ((ks * 4 + quad) ^ x7) * 8);
      bf16x8 bfr[2][2];
#pragma unroll
      for (int nj = 0; nj < 2; nj++)
#pragma unroll
        for (int ks = 0; ks < 2; ks++)
          bfr[nj][ks] = *(const bf16x8*)(bC + wn4 * 4096 + (nj * 16 + l15) * 64 +
                                         ((ks * 4 + quad) ^ x7) * 8);
      if (pf2) { stageB(tB2, kk2, 0); stageB(tB2, kk2, 1); stageB(tB2, kk2, 2); stageB(tB2, kk2, 3); }
      __builtin_amdgcn_s_barrier();
      __builtin_amdgcn_s_setprio(1);
#pragma unroll
      for (int ks = 0; ks < 2; ks++)
#pragma unroll
        for (int mi = 0; mi < 4; mi++)
#pragma unroll
          for (int nj = 0; nj < 2; nj++)
            acc[mi][nj] =
                __builtin_amdgcn_mfma_f32_16x16x32_bf16(afr[mi][ks], bfr[nj][ks], acc[mi][nj], 0, 0, 0);
      __builtin_amdgcn_s_setprio(0);
      __builtin_amdgcn_s_barrier();
    }

    // ---- phase 1: nj 2..3; stage A(T+2) x2 into a_sm[tt&1]; vmcnt(6) ----
    {
      bf16x8 bfr[2][2];
#pragma unroll
      for (int nj = 0; nj < 2; nj++)
#pragma unroll
        for (int ks = 0; ks < 2; ks++)
          bfr[nj][ks] = *(const bf16x8*)(bC + wn4 * 4096 + ((nj + 2) * 16 + l15) * 64 +
                                         ((ks * 4 + quad) ^ x7) * 8);
      if (pf2) {
        stageA(tt & 1, kk2, 0); stageA(tt & 1, kk2, 1);
        __asm__ volatile("s_waitcnt vmcnt(6)" ::: "memory");
      } else if (tt == NT2 - 2) {
        __asm__ volatile("s_waitcnt vmcnt(0)" ::: "memory");
      }
      __builtin_amdgcn_s_barrier();
      __builtin_amdgcn_s_setprio(1);
#pragma unroll
      for (int ks = 0; ks < 2; ks++)
#pragma unroll
        for (int mi = 0; mi < 4; mi++)
#pragma unroll
          for (int nj = 0; nj < 2; nj++)
            acc[mi][nj + 2] =
                __builtin_amdgcn_mfma_f32_16x16x32_bf16(afr[mi][ks], bfr[nj][ks], acc[mi][nj + 2], 0, 0, 0);
      __builtin_amdgcn_s_setprio(0);
      __builtin_amdgcn_s_barrier();
    }

    tB = (tB + 1 == 3) ? 0 : tB + 1;
  }

  // Epilogue.
  if (mode == 0) {
    const int mat = n0 >> 11;  // BN=256 divides 2048: block-uniform
    const float* bp = (mat == 0) ? b0 : (mat == 1) ? b1 : b2;
    const float sc2 = (mat == 0) ? qscale : 1.0f;
#pragma unroll
    for (int mi = 0; mi < 4; mi++) {
#pragma unroll
      for (int nj = 0; nj < 4; nj++) {
#pragma unroll
        for (int r = 0; r < 4; r++) {
          int row = m0 + wm2 * 64 + mi * 16 + quad * 4 + r;
          int col = n0 + wn4 * 64 + nj * 16 + l15;
          int cc = col & 2047;
          float v = (acc[mi][nj][r] + bp[cc]) * sc2;
          int l = row >> 1, nb = row & 1;
          int hh = cc >> 7, dd = cc & 127;
          out_bf[(size_t)mat * MROWS * II + ((size_t)(nb * NH + hh) * L_SEQ + l) * DH + dd] =
              f2bf(v);
        }
      }
    }
  } else {
#pragma unroll
    for (int mi = 0; mi < 4; mi++) {
#pragma unroll
      for (int nj = 0; nj < 4; nj++) {
#pragma unroll
        for (int r = 0; r < 4; r++) {
          int row = m0 + wm2 * 64 + mi * 16 + quad * 4 + r;
          int col = n0 + wn4 * 64 + nj * 16 + l15;
          out_f[(size_t)row * EMB + col] = acc[mi][nj][r] + b0[col];
        }
      }
    }
  }
}

// ---------------------------------------------------------------------------
// Causal flash attention v7: v6 structure (KVBLK=64, double-buffered K/V,
// wave-private P, one block barrier/iter) + FUSED V-TRANSPOSE staging:
// V is read directly from Vw [head][L][DH] (no Vt tensor, no transpose_v
// kernel). Per thread (vkq=t>>5 in 0..7 key-oct, vj=t&31 in 0..31 d-quad):
//   loads: 8x uint2 at V[(kb+8*vkq+i)*DH + 4*vj]  (lanes 0-31 cover 256B of a
//          key-row -> coalesced), issued at iteration TOP (T14 issue-early);
//   writes (after PV, write-late): 4x ds_write_b128 — row=4*vj+r holds keys
//          8*vkq..8*vkq+7 = exactly chunk vkq, at pos vkq^(row&7) — the SAME
//          swizzle contract the PV vf reads use, so PV code is unchanged.
// Next iteration's __syncthreads (lgkm+vm drain) publishes the writes.
// All vld/r indices compile-time (no scratch).
// ---------------------------------------------------------------------------
__global__ __launch_bounds__(256, 2) void flash_attn(
    const u16* __restrict__ Qh, const u16* __restrict__ Kh, const u16* __restrict__ Vr,
    u16* __restrict__ ctx) {
  __shared__ __align__(16) u16 k_sm[2][64 * 128];  // [buf][key][d], chunk-swizzled
  __shared__ __align__(16) u16 v_sm[2][128 * 64];  // [buf][d][key], chunk-swizzled
  __shared__ __align__(16) u16 p_sm[4][32 * 64];   // [wave][qrow][key], chunk-swizzled
  const int bx = blockIdx.x;
  const int nh = ((bx & 7) << 2) | ((bx >> 3) & 3);  // 4 heads per XCD
  const int g = (bx >> 5) & 7;
  const int qt = (bx < 256) ? (15 - g) : g;
  const int q0 = qt * 128;
  const int nK = 2 * (qt + 1);
  const int t = threadIdx.x;
  const int lane = t & 63, wv = t >> 6;
  const int quad = lane >> 4, l15 = lane & 15;
  const int x7 = l15 & 7;
  const size_t hq = (size_t)nh * L_SEQ * DH;
  const u16* qp = Qh + hq;
  const u16* kp = Kh + hq;
  const u16* vsrc = Vr + hq;  // [L][DH] per head (NOT transposed)
  const int n = nh >> 4, h = nh & 15;
  const int srow = lane >> 4;  // K staging: row-in-4 (256B rows)
  const int spos = lane & 15;
  const int vkq = t >> 5;      // 0..7  key-oct for V staging
  const int vj = t & 31;       // 0..31 d-quad for V staging
  u16* pwb = p_sm[wv];         // per-wave 4KB P slice

  uint2 vld[8];

  // K: async global->LDS (unchanged). V: 8x uint2 -> registers.
  auto stage_loads = [&](int bb, int kb) {
#pragma unroll
    for (int i = 0; i < 4; i++) {
      int ci = wv * 4 + i;  // 16 1KB units for K
      int krow = ci * 4 + srow;                    // 0..63
      int gck = spos ^ (krow & 7);
      gl_lds16(kp + (size_t)(kb + krow) * DH + gck * 8,
               (bb ? k_sm[1] : k_sm[0]) + ci * 512);
    }
#pragma unroll
    for (int i = 0; i < 8; i++)
      vld[i] = *(const uint2*)(vsrc + (size_t)(kb + 8 * vkq + i) * DH + 4 * vj);
  };
  // Transpose in-reg and write to v_sm[bb] ([d][key], chunk-swizzled).
  auto write_v = [&](int bb) {
    u16* vb = bb ? v_sm[1] : v_sm[0];
#pragma unroll
    for (int r = 0; r < 4; r++) {
      int row = 4 * vj + r;          // d-row 0..127; row&7 varies across lanes
      int pos = vkq ^ (row & 7);     // swizzle matches PV vf reads
      u32 w0 = (u32)((const u16*)&vld[0])[r] | ((u32)((const u16*)&vld[1])[r] << 16);
      u32 w1 = (u32)((const u16*)&vld[2])[r] | ((u32)((const u16*)&vld[3])[r] << 16);
      u32 w2 = (u32)((const u16*)&vld[4])[r] | ((u32)((const u16*)&vld[5])[r] << 16);
      u32 w3 = (u32)((const u16*)&vld[6])[r] | ((u32)((const u16*)&vld[7])[r] << 16);
      uint4 pk; pk.x = w0; pk.y = w1; pk.z = w2; pk.w = w3;
      *(uint4*)(vb + row * 64 + pos * 8) = pk;
    }
  };

  // Q fragments: rows q0 + wv*32 + mi*16 + l15.
  bf16x8 qf[2][4];
#pragma unroll
  for (int mi = 0; mi < 2; mi++)
#pragma unroll
    for (int ks = 0; ks < 4; ks++)
      qf[mi][ks] = *(const bf16x8*)(qp + (size_t)(q0 + wv * 32 + mi * 16 + l15) * DH +
                                    ks * 32 + quad * 8);

  f32x4 o_acc[2][8] = {};
  float l_part[2][4] = {};

  // Prologue: tile 0 -> buf 0 (loads, drain, transpose-write).
  stage_loads(0, 0);
  __asm__ volatile("s_waitcnt vmcnt(0)" ::: "memory");
  write_v(0);

#pragma unroll 1
  for (int jb = 0; jb < nK; jb++) {
    const int b = jb & 1;
    const u16* kbuf = b ? k_sm[1] : k_sm[0];
    const u16* vbuf = b ? v_sm[1] : v_sm[0];
    const int kb = jb * 64;

    // Drains lgkm (write_v of this tile) + vmcnt (K stage) and syncs waves.
    __syncthreads();
    if (jb + 1 < nK) stage_loads(b ^ 1, kb + 64);  // overlaps this iteration

    // S = Q K^T
    f32x4 s[2][4] = {};
    __builtin_amdgcn_s_setprio(1);
#pragma unroll
    for (int nt = 0; nt < 4; nt++) {
#pragma unroll
      for (int ks = 0; ks < 4; ks++) {
        bf16x8 kf = *(const bf16x8*)(kbuf + (nt * 16 + l15) * 128 + ((ks * 4 + quad) ^ x7) * 8);
#pragma unroll
        for (int mi = 0; mi < 2; mi++)
          s[mi][nt] = __builtin_amdgcn_mfma_f32_16x16x32_bf16(qf[mi][ks], kf, s[mi][nt], 0, 0, 0);
      }
    }
    __builtin_amdgcn_s_setprio(0);

    // Softmax -> wave-private P.
    const bool diag = (jb >= nK - 2);
#pragma unroll
    for (int mi = 0; mi < 2; mi++) {
      const int rowg = q0 + wv * 32 + mi * 16 + quad * 4;
#pragma unroll
      for (int nt = 0; nt < 4; nt++) {
        const int colg = kb + nt * 16 + l15;
#pragma unroll
        for (int r = 0; r < 4; r++) {
          float p = __builtin_amdgcn_exp2f(s[mi][nt][r]);
          if (diag && colg > rowg + r) p = 0.f;
          l_part[mi][r] += p;
          int pr = mi * 16 + quad * 4 + r;
          int chunk = nt * 2 + (l15 >> 3);
          int pos = chunk ^ (pr & 7);
          pwb[pr * 64 + pos * 8 + (l15 & 7)] = f2bf_trunc(p);
        }
      }
    }
    __asm__ volatile("s_waitcnt lgkmcnt(0)" ::: "memory");
    __builtin_amdgcn_sched_barrier(0);

    // O += P V
    bf16x8 pf[2][2];
#pragma unroll
    for (int mi = 0; mi < 2; mi++)
#pragma unroll
      for (int ks = 0; ks < 2; ks++)
        pf[mi][ks] = *(const bf16x8*)(pwb + (mi * 16 + l15) * 64 + ((ks * 4 + quad) ^ x7) * 8);
    __builtin_amdgcn_s_setprio(1);
#pragma unroll
    for (int nt = 0; nt < 8; nt++) {
#pragma unroll
      for (int ks = 0; ks < 2; ks++) {
        bf16x8 vf = *(const bf16x8*)(vbuf + (nt * 16 + l15) * 64 + ((ks * 4 + quad) ^ x7) * 8);
#pragma unroll
        for (int mi = 0; mi < 2; mi++)
          o_acc[mi][nt] =
              __builtin_amdgcn_mfma_f32_16x16x32_bf16(pf[mi][ks], vf, o_acc[mi][nt], 0, 0, 0);
      }
    }
    __builtin_amdgcn_s_setprio(0);

    // Write-late: publish next tile's V into v_sm[b^1] (disjoint from vbuf).
    if (jb + 1 < nK) {
      __asm__ volatile("s_waitcnt vmcnt(0)" ::: "memory");
      write_v(b ^ 1);
    }
  }

  // Epilogue: reduce denominators across the 16-lane row group, write ctx.
#pragma unroll
  for (int mi = 0; mi < 2; mi++) {
#pragma unroll
    for (int r = 0; r < 4; r++) {
      float lv = l_part[mi][r];
#pragma unroll
      for (int off = 1; off < 16; off <<= 1) lv += __shfl_xor(lv, off, 64);
      float inv = 1.f / lv;
      const int lrow = q0 + wv * 32 + mi * 16 + quad * 4 + r;
#pragma unroll
      for (int nt = 0; nt < 8; nt++) {
        int dd = nt * 16 + l15;
        ctx[((size_t)lrow * NB + n) * EMB + h * DH + dd] = f2bf(o_acc[mi][nt][r] * inv);
      }
    }
  }
}

extern "C" void kernel_launch(void* const* d_in, const int* in_sizes, int n_in,
                              void* d_out, int out_size, void* d_ws, size_t ws_size,
                              hipStream_t stream) {
  const float* query    = (const float*)d_in[0];
  const float* q_proj   = (const float*)d_in[1];
  const float* q_bias   = (const float*)d_in[2];
  const float* k_proj   = (const float*)d_in[3];
  const float* k_bias   = (const float*)d_in[4];
  const float* v_proj   = (const float*)d_in[5];
  const float* v_bias   = (const float*)d_in[6];
  const float* out_proj = (const float*)d_in[7];
  const float* out_bias = (const float*)d_in[8];

  u16* ws  = (u16*)d_ws;
  u16* Xbf = ws;                                  // 4096x2048 (dead after QKV gemm)
  u16* Wq  = Xbf + (size_t)MROWS * EMB;           // Wq|Wk|Wv contiguous = [6144,2048]
  u16* Wk  = Wq + (size_t)II * EMB;
  u16* Wv  = Wk + (size_t)II * EMB;
  u16* Wo  = Wv + (size_t)II * EMB;
  u16* Qw  = Wo + (size_t)EMB * II;               // [NB*NH][L][DH], Q|K|V contiguous
  u16* Kw  = Qw + (size_t)MROWS * II;
  u16* Vw  = Kw + (size_t)MROWS * II;
  u16* Cw  = Vw + (size_t)MROWS * II;             // ctx [L][NB][EMB]

  cast_all<<<8192 + 4 * 4096, 256, 0, stream>>>(query, q_proj, k_proj, v_proj, out_proj,
                                                Xbf, Wq);

  // d^-0.5 * log2(e): base-2 softmax
  const float qscale = 0.08838834764831845f * 1.4426950408889634f;
  gemm_2p<<<768, 512, 0, stream>>>(Xbf, Wq, q_bias, k_bias, v_bias, Qw, nullptr, qscale, 0);

  // transpose_v eliminated: flash stages V from Vw with in-register transpose.
  flash_attn<<<512, 256, 0, stream>>>(Qw, Kw, Vw, Cw);

  gemm_2p<<<256, 512, 0, stream>>>(Cw, Wo, out_bias, nullptr, nullptr, nullptr,
                                   (float*)d_out, 1.0f, 1);
}